// Round 2
// baseline (2190.428 us; speedup 1.0000x reference)
//
#include <hip/hip_runtime.h>
#include <hip/hip_fp16.h>

typedef _Float16 h2 __attribute__((ext_vector_type(2)));

#define AGENT __HIP_MEMORY_SCOPE_AGENT

constexpr float EPS_F    = 0.1f;
constexpr float NEG_IE   = -10.0f;   // -1/eps
constexpr float INV_EPS  = 10.0f;
constexpr float MU_P     = 0.0009765625f + 1e-8f;     // 1/1024 + 1e-8 (== nu)
constexpr float LOG_MU   = -6.9314615656526045f;      // log(MU_P)
constexpr float THRESH_B = 1.6f;                      // THRESH * B (sum-err compare)

// ---------------------------------------------------------------------------
// init: T slice0 = MU_P (so wv=1 at it=0), slices 1,2 = 0; errtab, ctr = 0.
__global__ __launch_bounds__(256) void init_kernel(
    float* __restrict__ T, float* __restrict__ errtab, int* __restrict__ ctr)
{
    int gid = blockIdx.x * 256 + threadIdx.x;
    if (gid < 49152) T[gid] = (gid < 16384) ? MU_P : 0.f;
    int g2 = gid - 49152;
    if (g2 >= 0 && g2 < 100) errtab[g2] = 0.f;
    int g3 = gid - 49252;
    if (g3 >= 0 && g3 < 1600) ctr[g3] = 0;
}

// ---------------------------------------------------------------------------
// sink: 256 blocks x 1024 threads, 1 block/CU, all resident (grid == #CU).
// Block (b = blk>>4, sub = blk&15) owns rows [64*sub, 64*sub+64) of batch b.
// Thread (w = tid>>6, l = tid&63) owns rows 64*sub+4w+r (r<4),
// cols {8l..8l+7} u {512+8l..512+8l+7}, E held in registers as half2.
// One per-batch 16-block spin barrier per iteration; T is a 3-slice rotation:
// read slice it%3, atomically accumulate slice (it+1)%3, zero slice (it+2)%3.
__global__ __launch_bounds__(1024) void sink_kernel(
    const float* __restrict__ C, float* __restrict__ T,
    float* __restrict__ errtab, int* __restrict__ ctr,
    _Float16* __restrict__ usnap, _Float16* __restrict__ vsnap,
    float* __restrict__ ufin, float* __restrict__ vfin)
{
    const int tid = threadIdx.x;
    const int l   = tid & 63;
    const int w   = tid >> 6;
    const int blk = blockIdx.x;
    const int b   = blk >> 4;
    const int sub = blk & 15;
    const int rb  = sub << 6;
    const int bofs = b << 10;

    __shared__ _Float16 wvh[1024];
    __shared__ float Tpart[16 * 1024];
    __shared__ float werr[16];

    // ---- load E = exp(-C/eps) into registers (once) ----
    h2 e2[4][2][4];
    {
        const float* Cb = C + ((size_t)b << 20);
        #pragma unroll
        for (int r = 0; r < 4; ++r) {
            const float4* Cp = (const float4*)(Cb + ((size_t)(rb + (w << 2) + r) << 10));
            #pragma unroll
            for (int g = 0; g < 2; ++g) {
                float4 a  = Cp[(l << 1) + (g << 7)];
                float4 c4 = Cp[(l << 1) + (g << 7) + 1];
                h2 t0; t0.x = (_Float16)__expf(NEG_IE * a.x);  t0.y = (_Float16)__expf(NEG_IE * a.y);
                h2 t1; t1.x = (_Float16)__expf(NEG_IE * a.z);  t1.y = (_Float16)__expf(NEG_IE * a.w);
                h2 t2; t2.x = (_Float16)__expf(NEG_IE * c4.x); t2.y = (_Float16)__expf(NEG_IE * c4.y);
                h2 t3; t3.x = (_Float16)__expf(NEG_IE * c4.z); t3.y = (_Float16)__expf(NEG_IE * c4.w);
                e2[r][g][0] = t0; e2[r][g][1] = t1; e2[r][g][2] = t2; e2[r][g][3] = t3;
            }
        }
    }

    float uold[4] = {0.f, 0.f, 0.f, 0.f};

    for (int it = 0; it < 100; ++it) {
        // ---- top: read T[it], build wv (fp16, LDS), zero slice it+2, v-snap ----
        float tv = __hip_atomic_load(&T[(it % 3) * 16384 + bofs + tid],
                                     __ATOMIC_RELAXED, AGENT);
        wvh[tid] = (_Float16)(MU_P / tv);
        if (it > 0 && w == sub)
            vsnap[(size_t)(it - 1) * 16384 + bofs + tid] =
                (_Float16)(EPS_F * (LOG_MU - __logf(tv)));
        if (w == sub)
            __hip_atomic_store(&T[((it + 2) % 3) * 16384 + bofs + rb + l], 0.f,
                               __ATOMIC_RELAXED, AGENT);
        __syncthreads();

        // ---- phase 1: row sums S_r = dot(E_row, wv) ----
        float s[4] = {0.f, 0.f, 0.f, 0.f};
        {
            const h2* wv2 = (const h2*)wvh;
            #pragma unroll
            for (int g = 0; g < 2; ++g) {
                h2 wv4[4];
                #pragma unroll
                for (int k = 0; k < 4; ++k) wv4[k] = wv2[(l << 2) + (g << 8) + k];
                #pragma unroll
                for (int r = 0; r < 4; ++r) {
                    #pragma unroll
                    for (int k = 0; k < 4; ++k)
                        s[r] = __builtin_amdgcn_fdot2(e2[r][g][k], wv4[k], s[r], false);
                }
            }
        }
        #pragma unroll
        for (int off = 1; off < 64; off <<= 1) {
            #pragma unroll
            for (int r = 0; r < 4; ++r) s[r] += __shfl_xor(s[r], off);
        }
        float wu[4], un[4], derr = 0.f;
        #pragma unroll
        for (int r = 0; r < 4; ++r) {
            un[r] = EPS_F * (LOG_MU - __logf(s[r]));
            derr += fabsf(un[r] - uold[r]);
            wu[r] = MU_P / s[r];
            uold[r] = un[r];
        }
        if (l == 0) {
            werr[w] = derr;
            h2 p0; p0.x = (_Float16)un[0]; p0.y = (_Float16)un[1];
            h2 p1; p1.x = (_Float16)un[2]; p1.y = (_Float16)un[3];
            h2* up = (h2*)(usnap + (size_t)it * 16384 + bofs + rb + (w << 2));
            up[0] = p0; up[1] = p1;
        }

        // ---- phase 2: per-thread column partials over its 4 rows ----
        float4 cs[4];
        #pragma unroll
        for (int g = 0; g < 2; ++g) {
            float4 c0 = {0.f, 0.f, 0.f, 0.f};
            float4 c1 = {0.f, 0.f, 0.f, 0.f};
            #pragma unroll
            for (int r = 0; r < 4; ++r) {
                float wr = wu[r];
                c0.x += wr * (float)e2[r][g][0].x;  c0.y += wr * (float)e2[r][g][0].y;
                c0.z += wr * (float)e2[r][g][1].x;  c0.w += wr * (float)e2[r][g][1].y;
                c1.x += wr * (float)e2[r][g][2].x;  c1.y += wr * (float)e2[r][g][2].y;
                c1.z += wr * (float)e2[r][g][3].x;  c1.w += wr * (float)e2[r][g][3].y;
            }
            cs[(g << 1)]     = c0;
            cs[(g << 1) + 1] = c1;
        }
        // conflict-free b128 exchange: Tpart[w][qb][l] (lane-contiguous float4)
        float4* Tp4 = (float4*)Tpart;
        #pragma unroll
        for (int qb = 0; qb < 4; ++qb)
            Tp4[(w << 8) + (qb << 6) + l] = cs[qb];
        __syncthreads();

        // ---- reduce 16 waves -> 1 global atomic per column (threads 0..255) ----
        if (tid < 256) {
            int l2 = tid & 63, qb2 = tid >> 6;
            float4 acc = {0.f, 0.f, 0.f, 0.f};
            #pragma unroll
            for (int w2 = 0; w2 < 16; ++w2) {
                float4 t4 = Tp4[(w2 << 8) + (qb2 << 6) + l2];
                acc.x += t4.x; acc.y += t4.y; acc.z += t4.z; acc.w += t4.w;
            }
            int c0 = (l2 << 3) + ((qb2 & 1) << 2) + ((qb2 >> 1) << 9);
            float* dst = &T[((it + 1) % 3) * 16384 + bofs + c0];
            __hip_atomic_fetch_add(dst + 0, acc.x, __ATOMIC_RELAXED, AGENT);
            __hip_atomic_fetch_add(dst + 1, acc.y, __ATOMIC_RELAXED, AGENT);
            __hip_atomic_fetch_add(dst + 2, acc.z, __ATOMIC_RELAXED, AGENT);
            __hip_atomic_fetch_add(dst + 3, acc.w, __ATOMIC_RELAXED, AGENT);
        } else if (w == 15) {
            float e = (l < 16) ? werr[l] : 0.f;
            #pragma unroll
            for (int off = 8; off >= 1; off >>= 1) e += __shfl_xor(e, off);
            if (l == 0)
                __hip_atomic_fetch_add(&errtab[it], e, __ATOMIC_RELAXED, AGENT);
        }
        __syncthreads();   // drains vmcnt: all global atomics complete before arrival

        // ---- per-batch 16-block barrier ----
        if (tid == 0) {
            __hip_atomic_fetch_add(&ctr[(it << 4) + b], 1, __ATOMIC_RELEASE, AGENT);
            while (__hip_atomic_load(&ctr[(it << 4) + b], __ATOMIC_ACQUIRE, AGENT) < 16) {}
        }
        __syncthreads();
    }

    // ---- finalize: f32 u,v after iteration 100 (the no-early-stop path) ----
    {
        float tv = __hip_atomic_load(&T[(100 % 3) * 16384 + bofs + tid],
                                     __ATOMIC_RELAXED, AGENT);
        if (w == sub) vfin[bofs + tid] = EPS_F * (LOG_MU - __logf(tv));
        if (l == 0) {
            float4* up = (float4*)(ufin + bofs + rb + (w << 2));
            up[0] = make_float4(uold[0], uold[1], uold[2], uold[3]);
        }
    }
}

// ---------------------------------------------------------------------------
// select: reconstruct freeze iteration t* from err table; if t* < 99 overwrite
// ufin/vfin from the fp16 snapshots (exact early-stop semantics).
__global__ __launch_bounds__(1024) void select_kernel(
    const float* __restrict__ errtab,
    const _Float16* __restrict__ usnap, const _Float16* __restrict__ vsnap,
    float* __restrict__ ufin, float* __restrict__ vfin)
{
    __shared__ int mn;
    if (threadIdx.x == 0) mn = 99;
    __syncthreads();
    if (threadIdx.x < 100 && errtab[threadIdx.x] < THRESH_B)
        atomicMin(&mn, (int)threadIdx.x);
    __syncthreads();
    int ti = mn;
    if (ti >= 99) return;   // common path: sink's f32 finals are correct
    int b = blockIdx.x & 15;
    size_t idx = (size_t)ti * 16384 + ((size_t)b << 10) + threadIdx.x;
    if (blockIdx.x < 16) ufin[(b << 10) + threadIdx.x] = (float)usnap[idx];
    else                 vfin[(b << 10) + threadIdx.x] = (float)vsnap[idx];
}

// ---------------------------------------------------------------------------
// epilogue: pi = exp((u_i + v_j - C_ij)/eps), copy C, per-row partial cost.
__global__ __launch_bounds__(256) void epilogue(
    const float* __restrict__ C, const float* __restrict__ ufin,
    const float* __restrict__ vfin,
    float* __restrict__ outPi, float* __restrict__ outC, float* __restrict__ part)
{
    int blk = blockIdx.x;
    int b = blk >> 10;
    int i = blk & 1023;
    size_t base = (size_t)blk << 10;
    const float4* C4 = (const float4*)(C + base);
    const float4* v4 = (const float4*)(vfin + ((size_t)b << 10));
    float4* P4 = (float4*)(outPi + base);
    float4* O4 = (float4*)(outC + base);
    float ui = ufin[(b << 10) + i];
    int t = threadIdx.x;
    float4 c = C4[t];
    float4 vv = v4[t];
    float4 p;
    p.x = __expf((ui + vv.x - c.x) * INV_EPS);
    p.y = __expf((ui + vv.y - c.y) * INV_EPS);
    p.z = __expf((ui + vv.z - c.z) * INV_EPS);
    p.w = __expf((ui + vv.w - c.w) * INV_EPS);
    P4[t] = p;
    O4[t] = c;
    float cp = p.x * c.x + p.y * c.y + p.z * c.z + p.w * c.w;
    #pragma unroll
    for (int off = 32; off >= 1; off >>= 1) cp += __shfl_xor(cp, off);
    __shared__ float ps[4];
    if ((t & 63) == 0) ps[t >> 6] = cp;
    __syncthreads();
    if (t == 0) part[blk] = ps[0] + ps[1] + ps[2] + ps[3];
}

__global__ __launch_bounds__(1024) void cost_reduce(
    const float* __restrict__ part, float* __restrict__ outCost)
{
    int b = blockIdx.x;
    int t = threadIdx.x;
    float s = part[(b << 10) + t];
    #pragma unroll
    for (int off = 32; off >= 1; off >>= 1) s += __shfl_xor(s, off);
    __shared__ float ps[16];
    if ((t & 63) == 0) ps[t >> 6] = s;
    __syncthreads();
    if (t < 64) {
        float e = (t < 16) ? ps[t] : 0.f;
        #pragma unroll
        for (int off = 8; off >= 1; off >>= 1) e += __shfl_xor(e, off);
        if (t == 0) outCost[b] = e;
    }
}

// ---------------------------------------------------------------------------
extern "C" void kernel_launch(void* const* d_in, const int* in_sizes, int n_in,
                              void* d_out, int out_size, void* d_ws, size_t ws_size,
                              hipStream_t stream)
{
    const float* C = (const float*)d_in[2];   // x,y unused (shapes only)
    float* out = (float*)d_out;

    // ws layout (~6.7 MB):
    char* ws = (char*)d_ws;
    float*    T      = (float*)(ws + 0);            // 3*16384 f32      (192 KB)
    float*    errtab = (float*)(ws + 196608);       // 100 f32
    int*      ctr    = (int*)  (ws + 197632);       // 1600 int
    _Float16* usnap  = (_Float16*)(ws + 204800);    // 100*16384 fp16   (3.125 MB)
    _Float16* vsnap  = (_Float16*)(ws + 3481600);   // 100*16384 fp16
    float*    ufin   = (float*)(ws + 6758400);      // 16384 f32
    float*    vfin   = (float*)(ws + 6823936);      // 16384 f32
    float*    part   = (float*)(ws + 6889472);      // 16384 f32

    init_kernel<<<199, 256, 0, stream>>>(T, errtab, ctr);
    sink_kernel<<<256, 1024, 0, stream>>>(C, T, errtab, ctr, usnap, vsnap, ufin, vfin);
    select_kernel<<<32, 1024, 0, stream>>>(errtab, usnap, vsnap, ufin, vfin);

    float* outPi = out + 16;
    float* outC  = out + 16 + (size_t)16777216;
    epilogue<<<16384, 256, 0, stream>>>(C, ufin, vfin, outPi, outC, part);
    cost_reduce<<<16, 1024, 0, stream>>>(part, out);
}

// Round 3
// 1745.367 us; speedup vs baseline: 1.2550x; 1.2550x over previous
//
#include <hip/hip_runtime.h>
#include <hip/hip_fp16.h>

typedef _Float16 h2 __attribute__((ext_vector_type(2)));

#define AGENT __HIP_MEMORY_SCOPE_AGENT

constexpr float EPS_F    = 0.1f;
constexpr float NEG_IE   = -10.0f;   // -1/eps
constexpr float INV_EPS  = 10.0f;
constexpr float MU_P     = 0.0009765625f + 1e-8f;     // 1/1024 + 1e-8 (== nu)
constexpr float LOG_MU   = -6.9314615656526045f;      // log(MU_P)
constexpr float THRESH_B = 1.6f;                      // THRESH * B (sum-err compare)

// ---------------------------------------------------------------------------
// init: T slice0 = MU_P (so wv=1 at it=0), slices 1,2 = 0; errtab, ctr = 0.
__global__ __launch_bounds__(256) void init_kernel(
    float* __restrict__ T, float* __restrict__ errtab, int* __restrict__ ctr)
{
    int gid = blockIdx.x * 256 + threadIdx.x;
    if (gid < 49152) T[gid] = (gid < 16384) ? MU_P : 0.f;
    int g2 = gid - 49152;
    if (g2 >= 0 && g2 < 100) errtab[g2] = 0.f;
    int g3 = gid - 49252;
    if (g3 >= 0 && g3 < 1600) ctr[g3] = 0;
}

// ---------------------------------------------------------------------------
// sink: 256 blocks x 1024 threads, 1 block/CU, all resident (grid == #CU).
// XCD-local mapping (blk%8 == XCD): batch b's 16 blocks all live on XCD b&7,
// so T-atomics / ctr-barrier / T-reads are XCD-L2-local.
// Block (b,sub) owns rows [64*sub, 64*sub+64) of batch b. Thread (w=tid>>6,
// l=tid&63) owns rows 64*sub+4w+r (r<4), cols {8l..8l+7} u {512+8l..512+8l+7};
// E = exp(-C/eps) held in 32 half2 VGPRs, loaded once.
// T is a 3-slice rotation: read slice it%3, accumulate slice (it+1)%3,
// zero slice (it+2)%3. One per-batch 16-block spin barrier per iteration.
__global__ __launch_bounds__(1024, 4) void sink_kernel(
    const float* __restrict__ C, float* __restrict__ T,
    float* __restrict__ errtab, int* __restrict__ ctr,
    _Float16* __restrict__ usnap, _Float16* __restrict__ vsnap,
    float* __restrict__ ufin, float* __restrict__ vfin)
{
    const int tid = threadIdx.x;
    const int l   = tid & 63;
    const int w   = tid >> 6;
    const int blk = blockIdx.x;
    const int b   = (blk & 7) | ((blk >> 7) << 3);   // XCD-local batch
    const int sub = (blk >> 3) & 15;
    const int rb  = sub << 6;
    const int bofs = b << 10;

    __shared__ _Float16 wvh[1024];
    __shared__ float Tpart[16 * 1024];
    __shared__ float werr[16];

    // ---- load E = exp(-C/eps) into registers (once) ----
    h2 e2[4][2][4];
    {
        const float* Cb = C + ((size_t)b << 20);
        #pragma unroll
        for (int r = 0; r < 4; ++r) {
            const float4* Cp = (const float4*)(Cb + ((size_t)(rb + (w << 2) + r) << 10));
            #pragma unroll
            for (int g = 0; g < 2; ++g) {
                float4 a  = Cp[(l << 1) + (g << 7)];
                float4 c4 = Cp[(l << 1) + (g << 7) + 1];
                h2 t0; t0.x = (_Float16)__expf(NEG_IE * a.x);  t0.y = (_Float16)__expf(NEG_IE * a.y);
                h2 t1; t1.x = (_Float16)__expf(NEG_IE * a.z);  t1.y = (_Float16)__expf(NEG_IE * a.w);
                h2 t2; t2.x = (_Float16)__expf(NEG_IE * c4.x); t2.y = (_Float16)__expf(NEG_IE * c4.y);
                h2 t3; t3.x = (_Float16)__expf(NEG_IE * c4.z); t3.y = (_Float16)__expf(NEG_IE * c4.w);
                e2[r][g][0] = t0; e2[r][g][1] = t1; e2[r][g][2] = t2; e2[r][g][3] = t3;
            }
        }
    }

    float uold[4] = {0.f, 0.f, 0.f, 0.f};

    for (int it = 0; it < 100; ++it) {
        // ---- top: read T[it], build wv (fp16, LDS), zero slice it+2, v-snap ----
        float tv = __hip_atomic_load(&T[(it % 3) * 16384 + bofs + tid],
                                     __ATOMIC_RELAXED, AGENT);
        wvh[tid] = (_Float16)(MU_P / tv);
        if (it > 0 && w == sub)
            vsnap[(size_t)(it - 1) * 16384 + bofs + tid] =
                (_Float16)(EPS_F * (LOG_MU - __logf(tv)));
        if (w == sub)
            __hip_atomic_store(&T[((it + 2) % 3) * 16384 + bofs + rb + l], 0.f,
                               __ATOMIC_RELAXED, AGENT);
        __syncthreads();

        // ---- phase 1: row sums S_r = dot(E_row, wv) ----
        float s[4] = {0.f, 0.f, 0.f, 0.f};
        {
            const uint4* wvq = (const uint4*)wvh;
            #pragma unroll
            for (int g = 0; g < 2; ++g) {
                union { uint4 q; h2 h[4]; } wv4;
                wv4.q = wvq[l + (g << 6)];              // ds_read_b128, conflict-free
                #pragma unroll
                for (int r = 0; r < 4; ++r) {
                    #pragma unroll
                    for (int k = 0; k < 4; ++k)
                        s[r] = __builtin_amdgcn_fdot2(e2[r][g][k], wv4.h[k], s[r], false);
                }
            }
        }
        #pragma unroll
        for (int off = 1; off < 64; off <<= 1) {
            #pragma unroll
            for (int r = 0; r < 4; ++r) s[r] += __shfl_xor(s[r], off);
        }
        float wu[4], derr = 0.f;
        #pragma unroll
        for (int r = 0; r < 4; ++r) {
            float un = EPS_F * (LOG_MU - __logf(s[r]));
            derr += fabsf(un - uold[r]);
            wu[r] = MU_P / s[r];
            uold[r] = un;
        }
        if (l == 0) {
            werr[w] = derr;
            h2 p0; p0.x = (_Float16)uold[0]; p0.y = (_Float16)uold[1];
            h2 p1; p1.x = (_Float16)uold[2]; p1.y = (_Float16)uold[3];
            h2* up = (h2*)(usnap + (size_t)it * 16384 + bofs + rb + (w << 2));
            up[0] = p0; up[1] = p1;
        }

        // ---- phase 2: per-thread column partials over its 4 rows ----
        float4 cs[4];
        #pragma unroll
        for (int g = 0; g < 2; ++g) {
            float4 c0 = {0.f, 0.f, 0.f, 0.f};
            float4 c1 = {0.f, 0.f, 0.f, 0.f};
            #pragma unroll
            for (int r = 0; r < 4; ++r) {
                float wr = wu[r];
                c0.x += wr * (float)e2[r][g][0].x;  c0.y += wr * (float)e2[r][g][0].y;
                c0.z += wr * (float)e2[r][g][1].x;  c0.w += wr * (float)e2[r][g][1].y;
                c1.x += wr * (float)e2[r][g][2].x;  c1.y += wr * (float)e2[r][g][2].y;
                c1.z += wr * (float)e2[r][g][3].x;  c1.w += wr * (float)e2[r][g][3].y;
            }
            cs[(g << 1)]     = c0;
            cs[(g << 1) + 1] = c1;
        }
        // conflict-free b128 exchange: Tpart[w][qb][l] (lane-contiguous float4)
        float4* Tp4 = (float4*)Tpart;
        #pragma unroll
        for (int qb = 0; qb < 4; ++qb)
            Tp4[(w << 8) + (qb << 6) + l] = cs[qb];
        __syncthreads();

        // ---- reduce 16 waves -> 1 global atomic per column (threads 0..255) ----
        if (tid < 256) {
            int l2 = tid & 63, qb2 = tid >> 6;
            float4 acc = {0.f, 0.f, 0.f, 0.f};
            #pragma unroll
            for (int w2 = 0; w2 < 16; ++w2) {
                float4 t4 = Tp4[(w2 << 8) + (qb2 << 6) + l2];
                acc.x += t4.x; acc.y += t4.y; acc.z += t4.z; acc.w += t4.w;
            }
            int c0 = (l2 << 3) + ((qb2 & 1) << 2) + ((qb2 >> 1) << 9);
            float* dst = &T[((it + 1) % 3) * 16384 + bofs + c0];
            __hip_atomic_fetch_add(dst + 0, acc.x, __ATOMIC_RELAXED, AGENT);
            __hip_atomic_fetch_add(dst + 1, acc.y, __ATOMIC_RELAXED, AGENT);
            __hip_atomic_fetch_add(dst + 2, acc.z, __ATOMIC_RELAXED, AGENT);
            __hip_atomic_fetch_add(dst + 3, acc.w, __ATOMIC_RELAXED, AGENT);
        } else if (w == 15) {
            float e = (l < 16) ? werr[l] : 0.f;
            #pragma unroll
            for (int off = 8; off >= 1; off >>= 1) e += __shfl_xor(e, off);
            if (l == 0)
                __hip_atomic_fetch_add(&errtab[it], e, __ATOMIC_RELAXED, AGENT);
        }
        __syncthreads();   // drains vmcnt: all global atomics complete before arrival

        // ---- per-batch 16-block barrier (XCD-local line) ----
        if (tid == 0) {
            __hip_atomic_fetch_add(&ctr[(it << 4) + b], 1, __ATOMIC_RELEASE, AGENT);
            while (__hip_atomic_load(&ctr[(it << 4) + b], __ATOMIC_ACQUIRE, AGENT) < 16) {}
        }
        __syncthreads();
    }

    // ---- finalize: f32 u,v after iteration 100 (the no-early-stop path) ----
    {
        float tv = __hip_atomic_load(&T[(100 % 3) * 16384 + bofs + tid],
                                     __ATOMIC_RELAXED, AGENT);
        if (w == sub) vfin[bofs + tid] = EPS_F * (LOG_MU - __logf(tv));
        if (l == 0) {
            float4* up = (float4*)(ufin + bofs + rb + (w << 2));
            up[0] = make_float4(uold[0], uold[1], uold[2], uold[3]);
        }
    }
}

// ---------------------------------------------------------------------------
// select: reconstruct freeze iteration t* from err table; if t* < 99 overwrite
// ufin/vfin from the fp16 snapshots (exact early-stop semantics).
__global__ __launch_bounds__(1024) void select_kernel(
    const float* __restrict__ errtab,
    const _Float16* __restrict__ usnap, const _Float16* __restrict__ vsnap,
    float* __restrict__ ufin, float* __restrict__ vfin)
{
    __shared__ int mn;
    if (threadIdx.x == 0) mn = 99;
    __syncthreads();
    if (threadIdx.x < 100 && errtab[threadIdx.x] < THRESH_B)
        atomicMin(&mn, (int)threadIdx.x);
    __syncthreads();
    int ti = mn;
    if (ti >= 99) return;   // common path: sink's f32 finals are correct
    int b = blockIdx.x & 15;
    size_t idx = (size_t)ti * 16384 + ((size_t)b << 10) + threadIdx.x;
    if (blockIdx.x < 16) ufin[(b << 10) + threadIdx.x] = (float)usnap[idx];
    else                 vfin[(b << 10) + threadIdx.x] = (float)vsnap[idx];
}

// ---------------------------------------------------------------------------
// epilogue: pi = exp((u_i + v_j - C_ij)/eps), copy C, per-row partial cost.
__global__ __launch_bounds__(256) void epilogue(
    const float* __restrict__ C, const float* __restrict__ ufin,
    const float* __restrict__ vfin,
    float* __restrict__ outPi, float* __restrict__ outC, float* __restrict__ part)
{
    int blk = blockIdx.x;
    int b = blk >> 10;
    int i = blk & 1023;
    size_t base = (size_t)blk << 10;
    const float4* C4 = (const float4*)(C + base);
    const float4* v4 = (const float4*)(vfin + ((size_t)b << 10));
    float4* P4 = (float4*)(outPi + base);
    float4* O4 = (float4*)(outC + base);
    float ui = ufin[(b << 10) + i];
    int t = threadIdx.x;
    float4 c = C4[t];
    float4 vv = v4[t];
    float4 p;
    p.x = __expf((ui + vv.x - c.x) * INV_EPS);
    p.y = __expf((ui + vv.y - c.y) * INV_EPS);
    p.z = __expf((ui + vv.z - c.z) * INV_EPS);
    p.w = __expf((ui + vv.w - c.w) * INV_EPS);
    P4[t] = p;
    O4[t] = c;
    float cp = p.x * c.x + p.y * c.y + p.z * c.z + p.w * c.w;
    #pragma unroll
    for (int off = 32; off >= 1; off >>= 1) cp += __shfl_xor(cp, off);
    __shared__ float ps[4];
    if ((t & 63) == 0) ps[t >> 6] = cp;
    __syncthreads();
    if (t == 0) part[blk] = ps[0] + ps[1] + ps[2] + ps[3];
}

__global__ __launch_bounds__(1024) void cost_reduce(
    const float* __restrict__ part, float* __restrict__ outCost)
{
    int b = blockIdx.x;
    int t = threadIdx.x;
    float s = part[(b << 10) + t];
    #pragma unroll
    for (int off = 32; off >= 1; off >>= 1) s += __shfl_xor(s, off);
    __shared__ float ps[16];
    if ((t & 63) == 0) ps[t >> 6] = s;
    __syncthreads();
    if (t < 64) {
        float e = (t < 16) ? ps[t] : 0.f;
        #pragma unroll
        for (int off = 8; off >= 1; off >>= 1) e += __shfl_xor(e, off);
        if (t == 0) outCost[b] = e;
    }
}

// ---------------------------------------------------------------------------
extern "C" void kernel_launch(void* const* d_in, const int* in_sizes, int n_in,
                              void* d_out, int out_size, void* d_ws, size_t ws_size,
                              hipStream_t stream)
{
    const float* C = (const float*)d_in[2];   // x,y unused (shapes only)
    float* out = (float*)d_out;

    // ws layout (~7 MB):
    char* ws = (char*)d_ws;
    float*    T      = (float*)(ws + 0);            // 3*16384 f32      (192 KB)
    float*    errtab = (float*)(ws + 196608);       // 100 f32
    int*      ctr    = (int*)  (ws + 197632);       // 1600 int
    _Float16* usnap  = (_Float16*)(ws + 204800);    // 100*16384 fp16   (3.125 MB)
    _Float16* vsnap  = (_Float16*)(ws + 3481600);   // 100*16384 fp16
    float*    ufin   = (float*)(ws + 6758400);      // 16384 f32
    float*    vfin   = (float*)(ws + 6823936);      // 16384 f32
    float*    part   = (float*)(ws + 6889472);      // 16384 f32

    init_kernel<<<199, 256, 0, stream>>>(T, errtab, ctr);
    sink_kernel<<<256, 1024, 0, stream>>>(C, T, errtab, ctr, usnap, vsnap, ufin, vfin);
    select_kernel<<<32, 1024, 0, stream>>>(errtab, usnap, vsnap, ufin, vfin);

    float* outPi = out + 16;
    float* outC  = out + 16 + (size_t)16777216;
    epilogue<<<16384, 256, 0, stream>>>(C, ufin, vfin, outPi, outC, part);
    cost_reduce<<<16, 1024, 0, stream>>>(part, out);
}